// Round 4
// baseline (300.544 us; speedup 1.0000x reference)
//
#include <hip/hip_runtime.h>

// AliasFreeActivation fused kernel, round 4:
//  - no xt LDS (phase A loads x directly from global, L1-cached overlap)
//  - bias folded algebraically into phase B: up(x+b)=up(x)+b*s(k0u)*s(k0v)
//  - C: 16 outputs/thread, D: 8 outputs/thread (fewer window re-reads)
//  - LDS 32224 B -> 5 blocks/CU; 3 barriers
//
// Math (verified rounds 1-3):
//  A  h-up:   t1[r][u] = sum_t f[k0+4t]*x[r][base-t], k0=(du+1)&3,
//             bb=((du+25-k0)>>2)-1 local in 8-float window x cols [2ug,2ug+7],
//             u=8ug+du. NO bias here.
//  B  v-up:   acc = sum_t f[k0v+4t]*t1[2vt8+bb-t][*] + b*s[k0u]*s[k0v],
//             then leaky*sqrt2. k0v=(dv+1)&3, bb=5+((dv+1)>>2), k0u=(cc+1)&3.
//  C  h-down: t2t[o][v] = sum_k g[k]*act[v][2o+11-k], 16 o's/thread.
//  D  v-down: out[8g+dv][ox] = sum_k g[k]*t2t[ox][16g+2dv+11-k], 8 rows/thread.
//
// LDS (words): act 74x76 @0 | t1 26x84 @5624 | t2t 32x76 @5624 (aliases t1,
//              live after B). Total 8056 w = 32224 B.

typedef float f4 __attribute__((ext_vector_type(4)));

#define ACTS4   19      // act stride in f4 (76 words)
#define T1OFF4  1406    // t1 offset in f4 (5624 words)
#define T1S4    21      // t1 stride in f4 (84 words)
#define T2TOFF  5624    // t2t offset in words
#define T2TS    76      // t2t stride in words
#define LDSW    8056

__global__ __launch_bounds__(256, 5) void afa_kernel(
    const float* __restrict__ x, const float* __restrict__ bias,
    const float* __restrict__ fup, const float* __restrict__ fdn,
    float* __restrict__ out)
{
    __shared__ __align__(16) float lds[LDSW];
    f4* lds4 = (f4*)lds;

    const int tid   = threadIdx.x;
    const int blk   = blockIdx.x;
    const int plane = blk >> 6;
    const int tile  = blk & 63;
    const int ty = tile >> 3, tx = tile & 7;

    float fr[24], gr[12];
    #pragma unroll
    for (int i = 0; i < 24; ++i) fr[i] = fup[i];
    #pragma unroll
    for (int i = 0; i < 12; ++i) gr[i] = fdn[i];

    // phase sums for bias fold: s[p] = sum_t f[p+4t]
    const float s0 = fr[0] + fr[4] + fr[8]  + fr[12] + fr[16] + fr[20];
    const float s1 = fr[1] + fr[5] + fr[9]  + fr[13] + fr[17] + fr[21];
    const float s2 = fr[2] + fr[6] + fr[10] + fr[14] + fr[18] + fr[22];
    const float s3 = fr[3] + fr[7] + fr[11] + fr[15] + fr[19] + fr[23];
    const float b  = bias[plane & 255];
    const f4 su4 = {s1, s2, s3, s0};              // s[(cc+1)&3]
    f4 bc[4];
    bc[0] = su4 * (b * s0);
    bc[1] = su4 * (b * s1);
    bc[2] = su4 * (b * s2);
    bc[3] = su4 * (b * s3);

    const int iy_base = 16 * ty + 1;
    const int ix_base = 16 * tx + 1;
    const float* xp = x + (size_t)plane * (128 * 128);

    // A: horizontal upsample, x read direct from global -> t1 (26 x 80 used)
    for (int task = tid; task < 260; task += 256) {
        int r = task / 10, ug = task - r * 10;
        const int iy = min(iy_base + r, 127);
        const float* row = xp + iy * 128;
        const int ix0 = ix_base + 2 * ug;
        float xw[8];
        #pragma unroll
        for (int m = 0; m < 8; ++m) xw[m] = row[min(ix0 + m, 127)];
        f4 res0, res1;
        #pragma unroll
        for (int du = 0; du < 8; ++du) {
            const int k0 = (du + 1) & 3;
            const int bb = ((du + 25 - k0) >> 2) - 1;
            float acc = 0.f;
            #pragma unroll
            for (int t = 0; t < 6; ++t) acc += fr[k0 + 4 * t] * xw[bb - t];
            if (du < 4) res0[du] = acc; else res1[du - 4] = acc;
        }
        lds4[T1OFF4 + r * T1S4 + 2 * ug]     = res0;
        lds4[T1OFF4 + r * T1S4 + 2 * ug + 1] = res1;
    }
    __syncthreads();

    // B: vertical upsample + bias + leaky*sqrt2 -> act (74 rows x 76 cols)
    if (tid < 190) {
        int vt8 = tid / 19, ut = tid - vt8 * 19;
        f4 w[8];
        #pragma unroll
        for (int m = 0; m < 8; ++m)
            w[m] = lds4[T1OFF4 + (2 * vt8 + m) * T1S4 + ut];
        #pragma unroll
        for (int dv = 0; dv < 8; ++dv) {
            const int row = 8 * vt8 + dv;
            if (row < 74) {
                const int k0 = (dv + 1) & 3;
                const int bb = 5 + ((dv + 1) >> 2);
                f4 acc = bc[k0];
                #pragma unroll
                for (int t = 0; t < 6; ++t) acc += fr[k0 + 4 * t] * w[bb - t];
                f4 r2;
                #pragma unroll
                for (int cc = 0; cc < 4; ++cc) {
                    float v = acc[cc];
                    r2[cc] = (v >= 0.f ? v : 0.2f * v) * 1.4142135623730951f;
                }
                lds4[row * ACTS4 + ut] = r2;
            }
        }
    }
    __syncthreads();

    // C: horizontal downsample -> t2t[o][v] (transposed), 16 o's/thread
    if (tid < 148) {
        const int v = tid >> 1, otg = tid & 1;
        union { f4 q[11]; float s[44]; } aw;
        #pragma unroll
        for (int j = 0; j < 11; ++j)
            aw.q[j] = lds4[v * ACTS4 + 8 * otg + j];
        #pragma unroll
        for (int i = 0; i < 16; ++i) {
            float acc = 0.f;
            #pragma unroll
            for (int k = 0; k < 12; ++k) acc += gr[k] * aw.s[2 * i + 11 - k];
            lds[T2TOFF + (16 * otg + i) * T2TS + v] = acc;
        }
    }
    __syncthreads();

    // D: vertical downsample from t2t, 8 rows x 1 col/thread, store to global
    if (tid < 128) {
        const int oy0 = ty * 32, ox0 = tx * 32;
        float* op = out + (size_t)plane * (236 * 236);
        const int ox = tid & 31, g = tid >> 5;
        union { f4 q[7]; float s[28]; } cw;
        #pragma unroll
        for (int j = 0; j < 7; ++j)
            cw.q[j] = lds4[T1OFF4 + ox * ACTS4 + 4 * g + j];
        const int oxg = ox0 + ox;
        #pragma unroll
        for (int dv = 0; dv < 8; ++dv) {
            float acc = 0.f;
            #pragma unroll
            for (int k = 0; k < 12; ++k) acc += gr[k] * cw.s[2 * dv + 11 - k];
            const int oy = oy0 + 8 * g + dv;
            if (oy < 236 && oxg < 236) op[oy * 236 + oxg] = acc;
        }
    }
}

extern "C" void kernel_launch(void* const* d_in, const int* in_sizes, int n_in,
                              void* d_out, int out_size, void* d_ws, size_t ws_size,
                              hipStream_t stream) {
    const float* x    = (const float*)d_in[0];
    const float* bias = (const float*)d_in[1];
    const float* fup  = (const float*)d_in[2];
    const float* fdn  = (const float*)d_in[3];
    float* out = (float*)d_out;

    dim3 grid(1024 * 64);
    dim3 block(256);
    afa_kernel<<<grid, block, 0, stream>>>(x, bias, fup, fdn, out);
}